// Round 3
// baseline (642.953 us; speedup 1.0000x reference)
//
#include <hip/hip_runtime.h>
#include <stdint.h>

// Problem constants: B=4, T=2048, D=1024, H=16, DH=64
#define B_  4
#define T_  2048
#define D_  1024
#define H_  16
#define DH_ 64

typedef unsigned short u16;
typedef __attribute__((ext_vector_type(8))) short bf16x8;   // 8 bf16 = 4 VGPRs
typedef __attribute__((ext_vector_type(8))) unsigned short u16x8;
typedef __attribute__((ext_vector_type(4))) float f32x4;

__device__ __forceinline__ u16 f2bf(float f) {
    union { float f; uint32_t u; } v; v.f = f;
    uint32_t r = v.u + 0x7FFFu + ((v.u >> 16) & 1u);   // RNE
    return (u16)(r >> 16);
}

// Load 8 consecutive elements starting at elem_off, returning bf16 u16x8.
// F32=true: source is fp32, convert with RNE. F32=false: source already bf16.
template<bool F32>
__device__ __forceinline__ u16x8 load8(const void* base, size_t elem_off) {
    if (F32) {
        const f32x4* p = (const f32x4*)((const float*)base + elem_off);
        f32x4 a = p[0], b = p[1];
        u16x8 o;
        o[0] = f2bf(a[0]); o[1] = f2bf(a[1]); o[2] = f2bf(a[2]); o[3] = f2bf(a[3]);
        o[4] = f2bf(b[0]); o[5] = f2bf(b[1]); o[6] = f2bf(b[2]); o[7] = f2bf(b[3]);
        return o;
    } else {
        return *(const u16x8*)((const u16*)base + elem_off);
    }
}

// ---------------------------------------------------------------------------
// C[M,N] = X[M,K] @ W[N,K]^T  (bf16 MFMA compute, fp32 accumulate)
// A_F32/B_F32: global operand dtype. O_F32: output dtype.
// Block: 256 thr = 4 waves, tile 128x128, waves in 2x2 of 64x64 subtiles.
// LDS stride 72 -> only 2-way bank aliasing (free).
// Staging: 256 thr x 8 elem x 4 passes = full 128x64 bf16 tile per matrix.
// ---------------------------------------------------------------------------
template<bool A_F32, bool B_F32, bool O_F32>
__global__ __launch_bounds__(256) void gemm_bt_kernel(
    const void* __restrict__ X, const void* __restrict__ W,
    void* __restrict__ C, int M, int N, int K)
{
    __shared__ __align__(16) u16 As[128 * 72];
    __shared__ __align__(16) u16 Bs[128 * 72];

    const int tid  = threadIdx.x;
    const int wave = tid >> 6;
    const int lane = tid & 63;
    const int lq = lane >> 4;      // quad 0..3
    const int lm = lane & 15;
    const int m0 = blockIdx.x * 128;
    const int n0 = blockIdx.y * 128;
    const int wm = (wave & 1) * 64;
    const int wn = (wave >> 1) * 64;

    f32x4 acc[4][4] = {};

    const int srow = tid >> 3;     // 0..31
    const int sch  = tid & 7;      // 8-element chunk 0..7 (full 64 k)

    for (int k0 = 0; k0 < K; k0 += 64) {
#pragma unroll
        for (int p = 0; p < 4; ++p) {
            int row = srow + p * 32;
            *(u16x8*)(As + row * 72 + sch * 8) =
                load8<A_F32>(X, (size_t)(m0 + row) * K + k0 + sch * 8);
            *(u16x8*)(Bs + row * 72 + sch * 8) =
                load8<B_F32>(W, (size_t)(n0 + row) * K + k0 + sch * 8);
        }
        __syncthreads();
#pragma unroll
        for (int ks = 0; ks < 2; ++ks) {
            bf16x8 af[4], bfr[4];
#pragma unroll
            for (int t = 0; t < 4; ++t)
                af[t] = *(const bf16x8*)(As + (wm + t * 16 + lm) * 72 + ks * 32 + lq * 8);
#pragma unroll
            for (int t = 0; t < 4; ++t)
                bfr[t] = *(const bf16x8*)(Bs + (wn + t * 16 + lm) * 72 + ks * 32 + lq * 8);
#pragma unroll
            for (int i = 0; i < 4; ++i)
#pragma unroll
                for (int j = 0; j < 4; ++j)
                    acc[i][j] = __builtin_amdgcn_mfma_f32_16x16x32_bf16(
                        af[i], bfr[j], acc[i][j], 0, 0, 0);
        }
        __syncthreads();
    }

#pragma unroll
    for (int i = 0; i < 4; ++i)
#pragma unroll
        for (int j = 0; j < 4; ++j)
#pragma unroll
            for (int r = 0; r < 4; ++r) {
                int row = m0 + wm + i * 16 + lq * 4 + r;
                int col = n0 + wn + j * 16 + lm;
                if (O_F32)
                    ((float*)C)[(size_t)row * N + col] = acc[i][j][r];
                else
                    ((u16*)C)[(size_t)row * N + col] = f2bf(acc[i][j][r]);
            }
}

// ---------------------------------------------------------------------------
// Flash-style causal attention over bf16 ws buffers (B,T,D) layout, head h
// at cols [h*64,h*64+64). One block = 64 Q rows of one (b,h); wave w owns
// rows w*16..w*16+15. K/V tiles of 64 keys in LDS (V transposed at stage).
// P (C-layout) round-trips per-wave LDS -> A-layout for the PV MFMA.
// ---------------------------------------------------------------------------
__global__ __launch_bounds__(256) void attn_kernel(
    const u16* __restrict__ Qg, const u16* __restrict__ Kg,
    const u16* __restrict__ Vg, u16* __restrict__ Og)
{
    __shared__ __align__(16) u16 Ks[64 * 72];     // [key][d]
    __shared__ __align__(16) u16 Vt[64 * 72];     // [d][key]
    __shared__ __align__(16) u16 Pl[4 * 16 * 72]; // per-wave 16x64 P

    const int tid  = threadIdx.x;
    const int wave = tid >> 6;
    const int lane = tid & 63;
    const int lq = lane >> 4, lm = lane & 15;
    const int qt = blockIdx.x;
    const int bh = blockIdx.y;
    const int b = bh / H_, h = bh % H_;
    const int q0 = qt * 64;

    const size_t batchoff = (size_t)b * T_ * D_;
    const size_t headoff  = (size_t)h * DH_;

    bf16x8 aq[2];
    {
        const u16* qrow = Qg + batchoff + (size_t)(q0 + wave * 16 + lm) * D_ + headoff;
        aq[0] = *(const bf16x8*)(qrow + 0 * 32 + lq * 8);
        aq[1] = *(const bf16x8*)(qrow + 1 * 32 + lq * 8);
    }

    f32x4 oacc[4] = {};
    float m_run[4], l_run[4];
#pragma unroll
    for (int r = 0; r < 4; ++r) { m_run[r] = -1e30f; l_run[r] = 0.0f; }

    const int srow = tid >> 3;   // 0..31
    const int sch  = tid & 7;    // full 64-wide head dim

    for (int kt = 0; kt <= qt; ++kt) {
#pragma unroll
        for (int p = 0; p < 2; ++p) {
            int row = srow + p * 32;
            const u16* ksrc = Kg + batchoff + (size_t)(kt * 64 + row) * D_ + headoff + sch * 8;
            *(u16x8*)(Ks + row * 72 + sch * 8) = *(const u16x8*)ksrc;
            const u16* vsrc = Vg + batchoff + (size_t)(kt * 64 + row) * D_ + headoff + sch * 8;
            u16x8 vv = *(const u16x8*)vsrc;
#pragma unroll
            for (int j = 0; j < 8; ++j)
                Vt[(sch * 8 + j) * 72 + row] = vv[j];
        }
        __syncthreads();

        // ---- S = Q K^T ----
        f32x4 s[4] = {};
#pragma unroll
        for (int ks = 0; ks < 2; ++ks) {
#pragma unroll
            for (int nt = 0; nt < 4; ++nt) {
                bf16x8 kf = *(const bf16x8*)(Ks + (nt * 16 + lm) * 72 + ks * 32 + lq * 8);
                s[nt] = __builtin_amdgcn_mfma_f32_16x16x32_bf16(aq[ks], kf, s[nt], 0, 0, 0);
            }
        }
#pragma unroll
        for (int nt = 0; nt < 4; ++nt) {
            int col = kt * 64 + nt * 16 + lm;
#pragma unroll
            for (int r = 0; r < 4; ++r) {
                int row = q0 + wave * 16 + lq * 4 + r;
                float v = s[nt][r] * 0.125f;   // 1/sqrt(64)
                s[nt][r] = (col > row) ? -1e9f : v;
            }
        }
        // ---- online softmax (rows live across the 16 lanes of a quad) ----
        float alpha[4];
#pragma unroll
        for (int r = 0; r < 4; ++r) {
            float mx = fmaxf(fmaxf(s[0][r], s[1][r]), fmaxf(s[2][r], s[3][r]));
#pragma unroll
            for (int off = 1; off < 16; off <<= 1)
                mx = fmaxf(mx, __shfl_xor(mx, off, 64));
            float nm = fmaxf(m_run[r], mx);
            alpha[r] = __expf(m_run[r] - nm);
            m_run[r] = nm;
            float rs = 0.0f;
#pragma unroll
            for (int nt = 0; nt < 4; ++nt) {
                float p = __expf(s[nt][r] - nm);
                s[nt][r] = p;
                rs += p;
            }
#pragma unroll
            for (int off = 1; off < 16; off <<= 1)
                rs += __shfl_xor(rs, off, 64);
            l_run[r] = l_run[r] * alpha[r] + rs;
        }
        // ---- P: C-layout regs -> per-wave LDS -> A-layout frags ----
        u16* pw = Pl + wave * 16 * 72;
#pragma unroll
        for (int nt = 0; nt < 4; ++nt)
#pragma unroll
            for (int r = 0; r < 4; ++r)
                pw[(lq * 4 + r) * 72 + nt * 16 + lm] = f2bf(s[nt][r]);
        __syncthreads();

#pragma unroll
        for (int nt = 0; nt < 4; ++nt)
#pragma unroll
            for (int r = 0; r < 4; ++r)
                oacc[nt][r] *= alpha[r];

        // ---- O += P V ----
#pragma unroll
        for (int ks = 0; ks < 2; ++ks) {
            bf16x8 ap = *(const bf16x8*)(pw + lm * 72 + ks * 32 + lq * 8);
#pragma unroll
            for (int nt = 0; nt < 4; ++nt) {
                bf16x8 bv = *(const bf16x8*)(Vt + (nt * 16 + lm) * 72 + ks * 32 + lq * 8);
                oacc[nt] = __builtin_amdgcn_mfma_f32_16x16x32_bf16(ap, bv, oacc[nt], 0, 0, 0);
            }
        }
        __syncthreads();   // protect Ks/Vt for next iteration
    }

    // ---- epilogue ----
    u16* obase = Og + batchoff + headoff;
#pragma unroll
    for (int nt = 0; nt < 4; ++nt)
#pragma unroll
        for (int r = 0; r < 4; ++r) {
            int row = q0 + wave * 16 + lq * 4 + r;
            float v = oacc[nt][r] / l_run[r];
            obase[(size_t)row * D_ + nt * 16 + lm] = f2bf(v);
        }
}

// ---------------------------------------------------------------------------
extern "C" void kernel_launch(void* const* d_in, const int* in_sizes, int n_in,
                              void* d_out, int out_size, void* d_ws, size_t ws_size,
                              hipStream_t stream)
{
    const void* x  = d_in[0];   // fp32 (B,T,D)
    // d_in[1] = mask (int32 tril) — causality hardcoded, not read
    const void* Wq = d_in[2];   // fp32 (D,D)
    const void* Wk = d_in[3];
    const void* Wv = d_in[4];
    const void* Wo = d_in[5];

    const size_t NT = (size_t)B_ * T_ * D_;   // 8.4M elements
    u16* Qb = (u16*)d_ws;
    u16* Kb = Qb + NT;
    u16* Vb = Kb + NT;
    u16* Ob = Vb + NT;

    const int M = B_ * T_;   // 8192
    dim3 gg(M / 128, D_ / 128);   // (64, 8)

    // fp32 inputs -> bf16 intermediates in ws
    gemm_bt_kernel<true, true, false><<<gg, 256, 0, stream>>>(x, Wq, Qb, M, D_, D_);
    gemm_bt_kernel<true, true, false><<<gg, 256, 0, stream>>>(x, Wk, Kb, M, D_, D_);
    gemm_bt_kernel<true, true, false><<<gg, 256, 0, stream>>>(x, Wv, Vb, M, D_, D_);

    attn_kernel<<<dim3(T_ / 64, B_ * H_), 256, 0, stream>>>(Qb, Kb, Vb, Ob);

    // bf16 attn-out @ fp32 Wo^T -> fp32 final output
    gemm_bt_kernel<false, true, true><<<gg, 256, 0, stream>>>(Ob, Wo, d_out, M, D_, D_);
}

// Round 4
// 452.167 us; speedup vs baseline: 1.4219x; 1.4219x over previous
//
#include <hip/hip_runtime.h>
#include <stdint.h>

// Problem constants: B=4, T=2048, D=1024, H=16, DH=64
#define B_  4
#define T_  2048
#define D_  1024
#define H_  16
#define DH_ 64

typedef unsigned short u16;
typedef __attribute__((ext_vector_type(8))) short bf16x8;   // 8 bf16 = 4 VGPRs
typedef __attribute__((ext_vector_type(8))) unsigned short u16x8;
typedef __attribute__((ext_vector_type(4))) float f32x4;

__device__ __forceinline__ u16 f2bf(float f) {
    union { float f; uint32_t u; } v; v.f = f;
    uint32_t r = v.u + 0x7FFFu + ((v.u >> 16) & 1u);   // RNE
    return (u16)(r >> 16);
}

// async 16B global->LDS (lds dest must be wave-uniform; HW adds lane*16)
__device__ __forceinline__ void gl2lds16(const u16* g, u16* l) {
    __builtin_amdgcn_global_load_lds(
        (const __attribute__((address_space(1))) unsigned int*)g,
        (__attribute__((address_space(3))) unsigned int*)l,
        16, 0, 0);
}

// ---------------------------------------------------------------------------
// fp32 -> bf16 converters
// ---------------------------------------------------------------------------
__global__ __launch_bounds__(256) void cvt_x_kernel(
    const float* __restrict__ src, u16* __restrict__ dst, int n8)
{
    int i = blockIdx.x * 256 + threadIdx.x;
    if (i >= n8) return;
    f32x4 a = ((const f32x4*)src)[2 * i];
    f32x4 b = ((const f32x4*)src)[2 * i + 1];
    u16x8 o;
    o[0]=f2bf(a[0]); o[1]=f2bf(a[1]); o[2]=f2bf(a[2]); o[3]=f2bf(a[3]);
    o[4]=f2bf(b[0]); o[5]=f2bf(b[1]); o[6]=f2bf(b[2]); o[7]=f2bf(b[3]);
    ((u16x8*)dst)[i] = o;
}

__global__ __launch_bounds__(256) void cvt_w_kernel(
    const float* __restrict__ w0, const float* __restrict__ w1,
    const float* __restrict__ w2, const float* __restrict__ w3,
    u16* __restrict__ dst)   // 4 consecutive D*D segments
{
    const float* src = (blockIdx.y == 0) ? w0 : (blockIdx.y == 1) ? w1
                     : (blockIdx.y == 2) ? w2 : w3;
    u16* d = dst + (size_t)blockIdx.y * (D_ * D_);
    int i = blockIdx.x * 256 + threadIdx.x;   // < D*D/8 = 131072
    f32x4 a = ((const f32x4*)src)[2 * i];
    f32x4 b = ((const f32x4*)src)[2 * i + 1];
    u16x8 o;
    o[0]=f2bf(a[0]); o[1]=f2bf(a[1]); o[2]=f2bf(a[2]); o[3]=f2bf(a[3]);
    o[4]=f2bf(b[0]); o[5]=f2bf(b[1]); o[6]=f2bf(b[2]); o[7]=f2bf(b[3]);
    ((u16x8*)d)[i] = o;
}

// ---------------------------------------------------------------------------
// C[M,N] = X[M,K] @ W[N,K]^T  (bf16 in, fp32 MFMA acc) — m97 structure:
// global_load_lds width-16 staging into UNPADDED 128x64 LDS tiles.
// OUT_MODE: 0 = bf16 natural, 1 = bf16 transposed-per-head [bh][dh][t],
//           2 = fp32 natural.
// ---------------------------------------------------------------------------
template<int OUT_MODE>
__global__ __launch_bounds__(256) void gemm_bt_kernel(
    const u16* __restrict__ X, const u16* __restrict__ W,
    void* __restrict__ C, int M, int N, int K)
{
    __shared__ __align__(16) u16 As[128 * 64];
    __shared__ __align__(16) u16 Bs[128 * 64];

    const int tid  = threadIdx.x;
    const int wave = tid >> 6;
    const int lane = tid & 63;
    const int lq = lane >> 4;      // quad 0..3
    const int lm = lane & 15;
    const int m0 = blockIdx.x * 128;
    const int n0 = blockIdx.y * 128;
    const int wm = (wave & 1) * 64;
    const int wn = (wave >> 1) * 64;

    f32x4 acc[4][4] = {};

    // staging map: wave w covers rows w*32..w*32+31; per call 8 rows
    // (64 lanes x 16B = 1KB); lane l -> row (l>>3), chunk (l&7).
    const int r0 = wave * 32 + (lane >> 3);
    const int c0 = (lane & 7) * 8;
    const u16* gA = X + (size_t)(m0 + r0) * K + c0;
    const u16* gB = W + (size_t)(n0 + r0) * K + c0;
    u16* lA = As + wave * 32 * 64;   // wave-uniform base
    u16* lB = Bs + wave * 32 * 64;

    for (int k0 = 0; k0 < K; k0 += 64) {
#pragma unroll
        for (int p = 0; p < 4; ++p) {
            gl2lds16(gA + (size_t)p * 8 * K + k0, lA + p * 8 * 64);
            gl2lds16(gB + (size_t)p * 8 * K + k0, lB + p * 8 * 64);
        }
        __syncthreads();   // drains vmcnt (global_load_lds) + lgkm
#pragma unroll
        for (int ks = 0; ks < 2; ++ks) {
            bf16x8 af[4], bfr[4];
#pragma unroll
            for (int t = 0; t < 4; ++t)
                af[t] = *(const bf16x8*)(As + (wm + t * 16 + lm) * 64 + ks * 32 + lq * 8);
#pragma unroll
            for (int t = 0; t < 4; ++t)
                bfr[t] = *(const bf16x8*)(Bs + (wn + t * 16 + lm) * 64 + ks * 32 + lq * 8);
#pragma unroll
            for (int i = 0; i < 4; ++i)
#pragma unroll
                for (int j = 0; j < 4; ++j)
                    acc[i][j] = __builtin_amdgcn_mfma_f32_16x16x32_bf16(
                        af[i], bfr[j], acc[i][j], 0, 0, 0);
        }
        __syncthreads();
    }

#pragma unroll
    for (int i = 0; i < 4; ++i)
#pragma unroll
        for (int j = 0; j < 4; ++j)
#pragma unroll
            for (int r = 0; r < 4; ++r) {
                int row = m0 + wm + i * 16 + lq * 4 + r;   // = b*T + t
                int col = n0 + wn + j * 16 + lm;           // = h*DH + dh
                if (OUT_MODE == 2) {
                    ((float*)C)[(size_t)row * N + col] = acc[i][j][r];
                } else if (OUT_MODE == 1) {
                    int b = row >> 11, t = row & (T_ - 1);
                    // [b*H+h][dh][t] = [col + b*D][t] since col = h*64+dh
                    ((u16*)C)[((size_t)b * D_ + col) * T_ + t] = f2bf(acc[i][j][r]);
                } else {
                    ((u16*)C)[(size_t)row * N + col] = f2bf(acc[i][j][r]);
                }
            }
}

// ---------------------------------------------------------------------------
// Flash-style causal attention. Q natural (B,T,D) bf16; K natural; V given
// PRE-TRANSPOSED per head: Vtg[(b*H+h)*DH + dh][t]. O natural bf16.
// Block = 128 Q rows of one (b,h); wave w owns rows w*32..w*32+31 (2 m-frags).
// K-tile = 64 keys. All staging is 16B vector load -> 16B LDS store.
// ---------------------------------------------------------------------------
__global__ __launch_bounds__(256) void attn_kernel(
    const u16* __restrict__ Qg, const u16* __restrict__ Kg,
    const u16* __restrict__ Vtg, u16* __restrict__ Og)
{
    __shared__ __align__(16) u16 Ks[64 * 72];      // [key][d]
    __shared__ __align__(16) u16 Vt[64 * 72];      // [d][key]
    __shared__ __align__(16) u16 Pl[4 * 32 * 72];  // per-wave 32x64 P

    const int tid  = threadIdx.x;
    const int wave = tid >> 6;
    const int lane = tid & 63;
    const int lq = lane >> 4, lm = lane & 15;
    const int qt = blockIdx.x;
    const int bh = blockIdx.y;
    const int b = bh >> 4, h = bh & 15;
    const int q0 = qt * 128;
    const int m0w = q0 + wave * 32;

    const size_t batchoff = (size_t)b * T_ * D_;
    const size_t headoff  = (size_t)h * DH_;
    const size_t vbase    = (size_t)bh * DH_ * T_;   // Vtg row block for this head

    // Q fragments (2 m-tiles x 2 k-chunks) live in registers
    bf16x8 aq[2][2];
#pragma unroll
    for (int mi = 0; mi < 2; ++mi) {
        const u16* qrow = Qg + batchoff + (size_t)(m0w + mi * 16 + lm) * D_ + headoff;
        aq[mi][0] = *(const bf16x8*)(qrow + 0 * 32 + lq * 8);
        aq[mi][1] = *(const bf16x8*)(qrow + 1 * 32 + lq * 8);
    }

    f32x4 oacc[2][4] = {};
    float m_run[2][4], l_run[2][4];
#pragma unroll
    for (int mi = 0; mi < 2; ++mi)
#pragma unroll
        for (int r = 0; r < 4; ++r) { m_run[mi][r] = -1e30f; l_run[mi][r] = 0.0f; }

    const int srow = tid >> 3;   // 0..31
    const int sch  = tid & 7;

    const int kt_max = 2 * qt + 1;
    for (int kt = 0; kt <= kt_max; ++kt) {
        // ---- stage K tile [key][d] and V^T tile [d][key], both 16B vec ----
#pragma unroll
        for (int p = 0; p < 2; ++p) {
            int row = p * 32 + srow;
            *(u16x8*)(Ks + row * 72 + sch * 8) =
                *(const u16x8*)(Kg + batchoff + (size_t)(kt * 64 + row) * D_ + headoff + sch * 8);
            *(u16x8*)(Vt + row * 72 + sch * 8) =
                *(const u16x8*)(Vtg + vbase + (size_t)row * T_ + kt * 64 + sch * 8);
        }
        __syncthreads();

        // wave-uniform causal skip: this wave's rows all < kt*64 -> fully masked
        if (kt * 64 <= m0w + 31) {
            // ---- S = Q K^T : 2 m-frags x 4 n-frags ----
            f32x4 s[2][4] = {};
#pragma unroll
            for (int ks = 0; ks < 2; ++ks) {
#pragma unroll
                for (int nt = 0; nt < 4; ++nt) {
                    bf16x8 kf = *(const bf16x8*)(Ks + (nt * 16 + lm) * 72 + ks * 32 + lq * 8);
#pragma unroll
                    for (int mi = 0; mi < 2; ++mi)
                        s[mi][nt] = __builtin_amdgcn_mfma_f32_16x16x32_bf16(
                            aq[mi][ks], kf, s[mi][nt], 0, 0, 0);
                }
            }
            // scale + causal mask
#pragma unroll
            for (int mi = 0; mi < 2; ++mi)
#pragma unroll
                for (int nt = 0; nt < 4; ++nt) {
                    int col = kt * 64 + nt * 16 + lm;
#pragma unroll
                    for (int r = 0; r < 4; ++r) {
                        int row = m0w + mi * 16 + lq * 4 + r;
                        float v = s[mi][nt][r] * 0.125f;   // 1/sqrt(64)
                        s[mi][nt][r] = (col > row) ? -1e9f : v;
                    }
                }
            // ---- online softmax ----
            float alpha[2][4];
#pragma unroll
            for (int mi = 0; mi < 2; ++mi)
#pragma unroll
                for (int r = 0; r < 4; ++r) {
                    float mx = fmaxf(fmaxf(s[mi][0][r], s[mi][1][r]),
                                     fmaxf(s[mi][2][r], s[mi][3][r]));
#pragma unroll
                    for (int off = 1; off < 16; off <<= 1)
                        mx = fmaxf(mx, __shfl_xor(mx, off, 64));
                    float nm = fmaxf(m_run[mi][r], mx);
                    alpha[mi][r] = __expf(m_run[mi][r] - nm);
                    m_run[mi][r] = nm;
                    float rs = 0.0f;
#pragma unroll
                    for (int nt = 0; nt < 4; ++nt) {
                        float p = __expf(s[mi][nt][r] - nm);
                        s[mi][nt][r] = p;
                        rs += p;
                    }
#pragma unroll
                    for (int off = 1; off < 16; off <<= 1)
                        rs += __shfl_xor(rs, off, 64);
                    l_run[mi][r] = l_run[mi][r] * alpha[mi][r] + rs;
                }
            // ---- P: C-layout -> per-wave LDS -> A-layout ----
            u16* pw = Pl + wave * 32 * 72;
#pragma unroll
            for (int mi = 0; mi < 2; ++mi)
#pragma unroll
                for (int nt = 0; nt < 4; ++nt)
#pragma unroll
                    for (int r = 0; r < 4; ++r)
                        pw[(mi * 16 + lq * 4 + r) * 72 + nt * 16 + lm] = f2bf(s[mi][nt][r]);
            // rescale O
#pragma unroll
            for (int mi = 0; mi < 2; ++mi)
#pragma unroll
                for (int nt = 0; nt < 4; ++nt)
#pragma unroll
                    for (int r = 0; r < 4; ++r)
                        oacc[mi][nt][r] *= alpha[mi][r];
            // ---- O += P V ---- (same-wave LDS RAW: compiler inserts lgkmcnt)
#pragma unroll
            for (int ks = 0; ks < 2; ++ks) {
                bf16x8 ap[2];
#pragma unroll
                for (int mi = 0; mi < 2; ++mi)
                    ap[mi] = *(const bf16x8*)(pw + (mi * 16 + lm) * 72 + ks * 32 + lq * 8);
#pragma unroll
                for (int nt = 0; nt < 4; ++nt) {
                    bf16x8 bv = *(const bf16x8*)(Vt + (nt * 16 + lm) * 72 + ks * 32 + lq * 8);
#pragma unroll
                    for (int mi = 0; mi < 2; ++mi)
                        oacc[mi][nt] = __builtin_amdgcn_mfma_f32_16x16x32_bf16(
                            ap[mi], bv, oacc[mi][nt], 0, 0, 0);
                }
            }
        }
        __syncthreads();   // protect Ks/Vt for next iteration
    }

    // ---- epilogue ----
    u16* obase = Og + batchoff + headoff;
#pragma unroll
    for (int mi = 0; mi < 2; ++mi)
#pragma unroll
        for (int nt = 0; nt < 4; ++nt)
#pragma unroll
            for (int r = 0; r < 4; ++r) {
                int row = m0w + mi * 16 + lq * 4 + r;
                float v = oacc[mi][nt][r] / l_run[mi][r];
                obase[(size_t)row * D_ + nt * 16 + lm] = f2bf(v);
            }
}

// ---------------------------------------------------------------------------
extern "C" void kernel_launch(void* const* d_in, const int* in_sizes, int n_in,
                              void* d_out, int out_size, void* d_ws, size_t ws_size,
                              hipStream_t stream)
{
    const float* x  = (const float*)d_in[0];   // fp32 (B,T,D)
    // d_in[1] = mask (int32 tril) — causality hardcoded, not read
    const float* Wq = (const float*)d_in[2];   // fp32 (D,D)
    const float* Wk = (const float*)d_in[3];
    const float* Wv = (const float*)d_in[4];
    const float* Wo = (const float*)d_in[5];

    const size_t NT = (size_t)B_ * T_ * D_;    // 8.4M elements
    const size_t DD = (size_t)D_ * D_;         // 1M elements
    u16* Qb  = (u16*)d_ws;
    u16* Kb  = Qb + NT;
    u16* Vb  = Kb + NT;       // transposed-per-head layout
    u16* Ob  = Vb + NT;
    u16* xb  = Ob + NT;
    u16* wb  = xb + NT;       // 4 x DD: Wq, Wk, Wv, Wo

    const int M = B_ * T_;    // 8192
    dim3 gg(M / 128, D_ / 128);   // (64, 8)

    // fp32 -> bf16 conversions
    cvt_x_kernel<<<dim3((int)(NT / 8 / 256)), 256, 0, stream>>>(x, xb, (int)(NT / 8));
    cvt_w_kernel<<<dim3((int)(DD / 8 / 256), 4), 256, 0, stream>>>(Wq, Wk, Wv, Wo, wb);

    // projections (bf16 m97-style GEMMs)
    gemm_bt_kernel<0><<<gg, 256, 0, stream>>>(xb, wb + 0 * DD, Qb, M, D_, D_);
    gemm_bt_kernel<0><<<gg, 256, 0, stream>>>(xb, wb + 1 * DD, Kb, M, D_, D_);
    gemm_bt_kernel<1><<<gg, 256, 0, stream>>>(xb, wb + 2 * DD, Vb, M, D_, D_);

    attn_kernel<<<dim3(T_ / 128, B_ * H_), 256, 0, stream>>>(Qb, Kb, Vb, Ob);

    // output projection -> fp32
    gemm_bt_kernel<2><<<gg, 256, 0, stream>>>(Ob, wb + 3 * DD, d_out, M, D_, D_);
}